// Round 13
// baseline (1768.867 us; speedup 1.0000x reference)
//
#include <hip/hip_runtime.h>
#include <hip/hip_bf16.h>
#include <stdint.h>

// VanillaTransformer: V=32000 S=2048 D=768 H=12 HD=64 L=6, batch=2 -> 4096 tokens
// r13: r12 with the gemmW LDS stride bug fixed (36864 -> 24576 u16; buf2 was
// entirely out of bounds). gemmW (256x128, 3-buf, counted vmcnt(6)) for
// qkv/fc1/decoder; proj/fc2 = split-K gemm_bb; attn v3 (proven).

typedef unsigned short u16;
typedef __attribute__((ext_vector_type(8))) __bf16 bf16x8;
typedef __attribute__((ext_vector_type(4))) float f32x4;
typedef __attribute__((ext_vector_type(4))) unsigned int u32x4;
typedef __attribute__((ext_vector_type(4))) unsigned short u16x4;
typedef __attribute__((ext_vector_type(8))) unsigned short u16x8;

#define MFMA16(a, b, c) __builtin_amdgcn_mfma_f32_16x16x32_bf16((a), (b), (c), 0, 0, 0)

__device__ __forceinline__ float b2f(u16 u) {
  union { unsigned int i; float f; } x; x.i = ((unsigned int)u) << 16; return x.f;
}
__device__ __forceinline__ u16 f2b(float f) {  // round-to-nearest-even
  union { float f; unsigned int i; } x; x.f = f;
  unsigned int r = x.i + 0x7fffu + ((x.i >> 16) & 1u);
  return (u16)(r >> 16);
}
__device__ __forceinline__ unsigned int cvtpk(float lo, float hi) {
  unsigned int r;
  asm("v_cvt_pk_bf16_f32 %0, %1, %2" : "=v"(r) : "v"(lo), "v"(hi));
  return r;
}
__device__ __forceinline__ float gelu_f(float v) {  // tanh-approx (jax default)
  const float t = 0.7978845608028654f * (v + 0.044715f * v * v * v);
  const float e = __expf(-2.f * fabsf(t));
  float th = (1.f - e) / (1.f + e);
  th = (t < 0.f) ? -th : th;
  return 0.5f * v * (1.f + th);
}
__device__ __forceinline__ void lds16(u16* l, const u16* g) {
  __builtin_amdgcn_global_load_lds(
      (const __attribute__((address_space(1))) unsigned int*)g,
      (__attribute__((address_space(3))) unsigned int*)l, 16, 0, 0);
}

// ---------------- f32 -> bf16 conversion (all 5 weights, one launch) ---------
__global__ __launch_bounds__(256) void conv5_kernel(
    const float* __restrict__ s0, u16* __restrict__ d0, int n0,
    const float* __restrict__ s1, u16* __restrict__ d1, int n1,
    const float* __restrict__ s2, u16* __restrict__ d2, int n2,
    const float* __restrict__ s3, u16* __restrict__ d3, int n3,
    const float* __restrict__ s4, u16* __restrict__ d4, int n4) {
  const float* src; u16* dst; int n8;
  switch (blockIdx.y) {
    case 0: src = s0; dst = d0; n8 = n0; break;
    case 1: src = s1; dst = d1; n8 = n1; break;
    case 2: src = s2; dst = d2; n8 = n2; break;
    case 3: src = s3; dst = d3; n8 = n3; break;
    default: src = s4; dst = d4; n8 = n4; break;
  }
  int i = blockIdx.x * 256 + threadIdx.x;
  const int stride = gridDim.x * 256;
  for (; i < n8; i += stride) {
    const f32x4 a = *(const f32x4*)&src[(size_t)i * 8];
    const f32x4 b = *(const f32x4*)&src[(size_t)i * 8 + 4];
    u16x8 p;
#pragma unroll
    for (int j = 0; j < 4; ++j) { p[j] = f2b(a[j]); p[4 + j] = f2b(b[j]); }
    *(u16x8*)&dst[(size_t)i * 8] = p;
  }
}

// ---------------- f32 -> bf16 (x -> h before decoder) ------------------------
__global__ __launch_bounds__(256) void convh_kernel(
    const float* __restrict__ src, u16* __restrict__ dst) {
  const int i = blockIdx.x * 256 + threadIdx.x;  // n8 = 393216
  const f32x4 a = *(const f32x4*)&src[(size_t)i * 8];
  const f32x4 b = *(const f32x4*)&src[(size_t)i * 8 + 4];
  u16x8 p;
#pragma unroll
  for (int j = 0; j < 4; ++j) { p[j] = f2b(a[j]); p[4 + j] = f2b(b[j]); }
  *(u16x8*)&dst[(size_t)i * 8] = p;
}

// ---------------- embedding --------------------------------------------------
__global__ __launch_bounds__(256) void embed_kernel(
    const int* __restrict__ idx, const float* __restrict__ tok,
    const float* __restrict__ pos, float* __restrict__ x) {
  const int t = blockIdx.x;
  const int s = t & 2047;
  const int tid = threadIdx.x;
  const size_t to = (size_t)idx[t] * 768;
  const size_t po = (size_t)s * 768;
  float* xr = x + (size_t)t * 768;
#pragma unroll
  for (int i = 0; i < 3; ++i) {
    const int d = tid + i * 256;
    xr[d] = tok[to + d] + pos[po + d];
  }
}

// ---------------- LayerNorm: wave-per-row ------------------------------------
__global__ __launch_bounds__(256) void ln_kernel(
    const float* __restrict__ x, const float* __restrict__ g,
    const float* __restrict__ b, u16* __restrict__ out) {
  const int w = threadIdx.x >> 6, lane = threadIdx.x & 63;
  const int row = blockIdx.x * 4 + w;
  const float* xr = x + (size_t)row * 768;
  f32x4 v[3];
#pragma unroll
  for (int i = 0; i < 3; ++i) v[i] = *(const f32x4*)&xr[i * 256 + lane * 4];
  float s = 0.f;
#pragma unroll
  for (int i = 0; i < 3; ++i)
#pragma unroll
    for (int j = 0; j < 4; ++j) s += v[i][j];
#pragma unroll
  for (int m = 1; m < 64; m <<= 1) s += __shfl_xor(s, m);
  const float mu = s * (1.f / 768.f);
  float q = 0.f;
#pragma unroll
  for (int i = 0; i < 3; ++i)
#pragma unroll
    for (int j = 0; j < 4; ++j) {
      const float d = v[i][j] - mu;
      q += d * d;
    }
#pragma unroll
  for (int m = 1; m < 64; m <<= 1) q += __shfl_xor(q, m);
  const float rs = rsqrtf(q * (1.f / 768.f) + 1e-5f);
  u16* orow = out + (size_t)row * 768;
#pragma unroll
  for (int i = 0; i < 3; ++i) {
    const f32x4 gg = *(const f32x4*)&g[i * 256 + lane * 4];
    const f32x4 bb = *(const f32x4*)&b[i * 256 + lane * 4];
    u16x4 o;
#pragma unroll
    for (int j = 0; j < 4; ++j) o[j] = f2b((v[i][j] - mu) * rs * gg[j] + bb[j]);
    *(u16x4*)&orow[i * 256 + lane * 4] = o;
  }
}

// ===== gemmW: 256x128 tile, 8 waves (4M x 2N), BK=64, 3-buf counted-vmcnt ====
// C[M,N] = A[M,K](bf16) * B[N,K](bf16)^T. M%256==0, N%128==0, K%64==0, K/64>=3.
// LDS 144KB = 3 bufs x 24576 u16 (A[256][64] 16384 u16 + B[128][64] 8192 u16).
// 128B row stride + XOR slot swizzle (gemm_bb-proven conflict-free).
// Ledger: tile j -> buf j%3; stage(t+2) issued after barrier of tile t;
// vmcnt(6) at tile-t entry retires exactly tile t's 6 loads/wave, leaves
// t+1's 6 in flight. vmcnt(0) only at last tile.
// MODE 0: outb=bf16(acc+bias)  1: +gelu  3: outf f32 nontemporal
// MODE 4: qkv epilogue (cols>=1536 -> V^T into mirror)
template <int MODE>
__global__ __launch_bounds__(512, 1) void gemmW(
    const u16* __restrict__ A, const u16* __restrict__ B,
    const float* __restrict__ bias, u16* __restrict__ outb,
    float* __restrict__ outf, u16* __restrict__ mirror, int N, int K) {
  extern __shared__ u16 smw[];  // 3 * 24576 u16 = 147456 B
  const int tid = threadIdx.x;
  const int lane = tid & 63;
  const int w = tid >> 6;
  const int wm = w >> 1;  // 0..3 (row 64-block)
  const int wn = w & 1;   // 0..1 (col 64-block)
  const int fr = lane & 15;
  const int fg = lane >> 4;
  const int bm0 = blockIdx.x * 256;
  const int bn0 = blockIdx.y * 128;
  const int nt = K >> 6;

  f32x4 acc[4][4] = {};

  auto stageT = [&](int buf, int t) {
    const int k0 = t << 6;
    u16* Ab = smw + buf * 24576;
    u16* Bb = smw + buf * 24576 + 16384;
#pragma unroll
    for (int i = 0; i < 4; ++i) {  // A: 2048 chunks of 16B
      const int c = i * 512 + tid;
      const int row = c >> 3;
      const int slot = (c & 7) ^ (row & 7);
      lds16(Ab + (i * 512 + w * 64) * 8,
            A + (size_t)(bm0 + row) * K + k0 + slot * 8);
    }
#pragma unroll
    for (int i = 0; i < 2; ++i) {  // B: 1024 chunks of 16B
      const int c = i * 512 + tid;
      const int row = c >> 3;
      const int slot = (c & 7) ^ (row & 7);
      lds16(Bb + (i * 512 + w * 64) * 8,
            B + (size_t)(bn0 + row) * K + k0 + slot * 8);
    }
  };

  stageT(0, 0);
  stageT(1, 1);
  int buf = 0;
  for (int t = 0; t < nt; ++t) {
    if (t + 1 < nt)
      asm volatile("s_waitcnt vmcnt(6)" ::: "memory");
    else
      asm volatile("s_waitcnt vmcnt(0)" ::: "memory");
    __builtin_amdgcn_sched_barrier(0);
    __builtin_amdgcn_s_barrier();
    __builtin_amdgcn_sched_barrier(0);
    if (t + 2 < nt) stageT((buf + 2) % 3, t + 2);
    const u16* Ab = smw + buf * 24576;
    const u16* Bb = smw + buf * 24576 + 16384;

    bf16x8 af[2][4], bfv[2][2];
    // phase 0: all A-frags + B-frags n=0,1; 16 MFMA
#pragma unroll
    for (int kx = 0; kx < 2; ++kx)
#pragma unroll
      for (int m = 0; m < 4; ++m) {
        const int row = wm * 64 + m * 16 + fr;
        const int slot = (kx * 4 + fg) ^ (row & 7);
        af[kx][m] = *(const bf16x8*)&Ab[row * 64 + slot * 8];
      }
#pragma unroll
    for (int kx = 0; kx < 2; ++kx)
#pragma unroll
      for (int n = 0; n < 2; ++n) {
        const int row = wn * 64 + n * 16 + fr;
        const int slot = (kx * 4 + fg) ^ (row & 7);
        bfv[kx][n] = *(const bf16x8*)&Bb[row * 64 + slot * 8];
      }
    __builtin_amdgcn_s_setprio(1);
#pragma unroll
    for (int kx = 0; kx < 2; ++kx)
#pragma unroll
      for (int m = 0; m < 4; ++m)
#pragma unroll
        for (int n = 0; n < 2; ++n)
          acc[m][n] = MFMA16(af[kx][m], bfv[kx][n], acc[m][n]);
    __builtin_amdgcn_s_setprio(0);
    // phase 1: B-frags n=2,3; 16 MFMA (A reused from regs)
#pragma unroll
    for (int kx = 0; kx < 2; ++kx)
#pragma unroll
      for (int n = 0; n < 2; ++n) {
        const int row = wn * 64 + (2 + n) * 16 + fr;
        const int slot = (kx * 4 + fg) ^ (row & 7);
        bfv[kx][n] = *(const bf16x8*)&Bb[row * 64 + slot * 8];
      }
    __builtin_amdgcn_s_setprio(1);
#pragma unroll
    for (int kx = 0; kx < 2; ++kx)
#pragma unroll
      for (int m = 0; m < 4; ++m)
#pragma unroll
        for (int n = 0; n < 2; ++n)
          acc[m][2 + n] = MFMA16(af[kx][m], bfv[kx][n], acc[m][2 + n]);
    __builtin_amdgcn_s_setprio(0);
    buf = (buf + 1) % 3;
  }

  if (MODE == 4 && bn0 >= 1536) {
#pragma unroll
    for (int n = 0; n < 4; ++n) {
      const int col = bn0 + wn * 64 + n * 16 + fr;
      const float bv = bias[col];
      const int hcol = col - 1536;
      const size_t vbase =
          (size_t)(hcol >> 6) * 64 * 2048 + (size_t)(hcol & 63) * 2048;
#pragma unroll
      for (int m = 0; m < 4; ++m) {
        const int row0 = bm0 + wm * 64 + m * 16 + fg * 4;
        const size_t bboff = (size_t)(row0 >> 11) * 12 * 64 * 2048;
        const int s = row0 & 2047;
        u16x4 o;
#pragma unroll
        for (int r = 0; r < 4; ++r) o[r] = f2b(acc[m][n][r] + bv);
        *(u16x4*)&mirror[bboff + vbase + s] = o;
      }
    }
    return;
  }

#pragma unroll
  for (int n = 0; n < 4; ++n) {
    const int col = bn0 + wn * 64 + n * 16 + fr;
    const float bv = bias ? bias[col] : 0.0f;
#pragma unroll
    for (int m = 0; m < 4; ++m) {
#pragma unroll
      for (int r = 0; r < 4; ++r) {
        const int row = bm0 + wm * 64 + m * 16 + fg * 4 + r;
        float v = acc[m][n][r] + bv;
        if (MODE == 1) v = gelu_f(v);
        const size_t off = (size_t)row * N + col;
        if (MODE == 3) {
          __builtin_nontemporal_store(v, &outf[off]);
        } else {
          outb[off] = f2b(v);
        }
      }
    }
  }
}

// ===== gemm_bb 128^2, double-buffered, lds16+XOR swizzle =====================
// MODE 2: resid+= (RMW single owner)  5: atomicAdd (split-K; bias on z==0)
template <int MODE, int MFAST, int SPLITK>
__global__ __launch_bounds__(256) void gemm_bb(
    const u16* __restrict__ A, const u16* __restrict__ B,
    const float* __restrict__ bias, u16* __restrict__ outb,
    float* __restrict__ outf, float* __restrict__ resid,
    u16* __restrict__ mirror, int N, int K) {
  __shared__ alignas(16) u16 As[2][128 * 64];
  __shared__ alignas(16) u16 Bs[2][128 * 64];
  const int tid = threadIdx.x;
  const int lane = tid & 63;
  const int w = tid >> 6;
  const int wr = (w >> 1) * 64;
  const int wc = (w & 1) * 64;
  const int fr = lane & 15;
  const int fg = lane >> 4;
  const int bn0 = (MFAST ? blockIdx.y : blockIdx.x) * 128;
  const int bm0 = (MFAST ? blockIdx.x : blockIdx.y) * 128;
  const int srow = tid >> 3;
  const int kseg = K / SPLITK;
  const int kbeg = (SPLITK > 1) ? blockIdx.z * kseg : 0;
  const int kend = kbeg + kseg;

  f32x4 acc[4][4] = {};

  auto stage = [&](int bufq, int bk0) {
#pragma unroll
    for (int i = 0; i < 4; ++i) {
      const int row = i * 32 + srow;
      const int slot = (tid & 7) ^ (row & 7);
      lds16(&As[bufq][(i * 256 + w * 64) * 8],
            &A[(size_t)(bm0 + row) * K + bk0 + slot * 8]);
      lds16(&Bs[bufq][(i * 256 + w * 64) * 8],
            &B[(size_t)(bn0 + row) * K + bk0 + slot * 8]);
    }
  };

  stage(0, kbeg);
  int cur = 0;
  for (int bk0 = kbeg; bk0 < kend; bk0 += 64) {
    __syncthreads();
    if (bk0 + 64 < kend) stage(cur ^ 1, bk0 + 64);
#pragma unroll
    for (int kk = 0; kk < 64; kk += 32) {
      bf16x8 af[4], bfv[4];
#pragma unroll
      for (int m = 0; m < 4; ++m) {
        const int row = wr + m * 16 + fr;
        const int slot = ((kk >> 3) + fg) ^ (row & 7);
        af[m] = *(const bf16x8*)&As[cur][row * 64 + slot * 8];
      }
#pragma unroll
      for (int n = 0; n < 4; ++n) {
        const int row = wc + n * 16 + fr;
        const int slot = ((kk >> 3) + fg) ^ (row & 7);
        bfv[n] = *(const bf16x8*)&Bs[cur][row * 64 + slot * 8];
      }
#pragma unroll
      for (int m = 0; m < 4; ++m)
#pragma unroll
        for (int n = 0; n < 4; ++n)
          acc[m][n] = MFMA16(af[m], bfv[n], acc[m][n]);
    }
    cur ^= 1;
  }

#pragma unroll
  for (int n = 0; n < 4; ++n) {
    const int col = bn0 + wc + n * 16 + fr;
    const float bv =
        (bias && (SPLITK == 1 || blockIdx.z == 0)) ? bias[col] : 0.0f;
#pragma unroll
    for (int m = 0; m < 4; ++m) {
#pragma unroll
      for (int r = 0; r < 4; ++r) {
        const int row = bm0 + wr + m * 16 + fg * 4 + r;
        float v = acc[m][n][r] + bv;
        if (MODE == 1) v = gelu_f(v);
        const size_t off = (size_t)row * N + col;
        if (MODE == 2) {
          const float nv = resid[off] + v;
          resid[off] = nv;
          if (mirror) mirror[off] = f2b(nv);
        } else if (MODE == 5) {
          atomicAdd(&resid[off], v);
        } else if (MODE == 3) {
          __builtin_nontemporal_store(v, &outf[off]);
        } else {
          outb[off] = f2b(v);
        }
      }
    }
  }
}

// ===== fallback GEMM (B is f32, converted during staging) ====================
template <int MODE>
__global__ __launch_bounds__(256) void gemm_bt(
    const u16* __restrict__ A, const float* __restrict__ B,
    const float* __restrict__ bias, u16* __restrict__ outb,
    float* __restrict__ outf, float* __restrict__ resid,
    u16* __restrict__ mirror, int N, int K) {
  __shared__ alignas(16) u16 As[128 * 64];
  __shared__ alignas(16) u16 Bs[128 * 64];
  const int tid = threadIdx.x;
  const int lane = tid & 63;
  const int w = tid >> 6;
  const int wr = (w >> 1) * 64;
  const int wc = (w & 1) * 64;
  const int fr = lane & 15;
  const int fg = lane >> 4;
  const int bn0 = blockIdx.x * 128;
  const int bm0 = blockIdx.y * 128;

  f32x4 acc[4][4] = {};

  for (int bk0 = 0; bk0 < K; bk0 += 64) {
    __syncthreads();
#pragma unroll
    for (int i = 0; i < 4; ++i) {
      const int c = i * 256 + tid;
      const int row = c >> 3;
      const int e0 = (c & 7) * 8;
      *(u32x4*)&As[row * 64 + e0] =
          *(const u32x4*)&A[(size_t)(bm0 + row) * K + bk0 + e0];
    }
#pragma unroll
    for (int i = 0; i < 8; ++i) {
      const int c = i * 256 + tid;
      const int row = c >> 4;
      const int e0 = (c & 15) * 4;
      const f32x4 fv = *(const f32x4*)&B[(size_t)(bn0 + row) * K + bk0 + e0];
      u16x4 pv;
#pragma unroll
      for (int j = 0; j < 4; ++j) pv[j] = f2b(fv[j]);
      *(u16x4*)&Bs[row * 64 + e0] = pv;
    }
    __syncthreads();
#pragma unroll
    for (int kk = 0; kk < 64; kk += 32) {
      bf16x8 af[4], bfv[4];
#pragma unroll
      for (int m = 0; m < 4; ++m)
        af[m] = *(const bf16x8*)&As[(wr + m * 16 + fr) * 64 + kk + fg * 8];
#pragma unroll
      for (int n = 0; n < 4; ++n)
        bfv[n] = *(const bf16x8*)&Bs[(wc + n * 16 + fr) * 64 + kk + fg * 8];
#pragma unroll
      for (int m = 0; m < 4; ++m)
#pragma unroll
        for (int n = 0; n < 4; ++n)
          acc[m][n] = MFMA16(af[m], bfv[n], acc[m][n]);
    }
  }

#pragma unroll
  for (int n = 0; n < 4; ++n) {
    const int col = bn0 + wc + n * 16 + fr;
    const float bv = bias ? bias[col] : 0.0f;
#pragma unroll
    for (int m = 0; m < 4; ++m) {
#pragma unroll
      for (int r = 0; r < 4; ++r) {
        const int row = bm0 + wr + m * 16 + fg * 4 + r;
        float v = acc[m][n][r] + bv;
        if (MODE == 1) v = gelu_f(v);
        const size_t off = (size_t)row * N + col;
        if (MODE == 2) {
          const float nv = resid[off] + v;
          resid[off] = nv;
          if (mirror) mirror[off] = f2b(nv);
        } else if (MODE == 3) {
          __builtin_nontemporal_store(v, &outf[off]);
        } else {
          outb[off] = f2b(v);
        }
      }
    }
  }
}

// ---------------- V transpose (fallback path only) ---------------------------
__global__ __launch_bounds__(256) void vtrans_kernel(
    const u16* __restrict__ qkv, u16* __restrict__ vt) {
  __shared__ u16 tile[64][72];
  const int tid = threadIdx.x;
  const int s0 = blockIdx.x * 64;
  const int hh = blockIdx.y;
  const int bb = blockIdx.z;
  const size_t tb = (size_t)bb * 2048 * 2304;
#pragma unroll
  for (int i = 0; i < 2; ++i) {
    const int c = i * 256 + tid;
    const int sl = c >> 3;
    const int d0 = (c & 7) * 8;
    *(u16x8*)&tile[sl][d0] =
        *(const u16x8*)&qkv[tb + (size_t)(s0 + sl) * 2304 + 1536 + hh * 64 + d0];
  }
  __syncthreads();
  const size_t vtb = (size_t)((bb * 12 + hh) * 64) * 2048;
#pragma unroll
  for (int i = 0; i < 2; ++i) {
    const int c = i * 256 + tid;
    const int d = c >> 3;
    const int so = (c & 7) * 8;
    u16x8 p;
#pragma unroll
    for (int j = 0; j < 8; ++j) p[j] = tile[so + j][d];
    *(u16x8*)&vt[vtb + (size_t)d * 2048 + s0 + so] = p;
  }
}

// ---------------- fused attention v3 (proven): swapped QK^T ------------------
__global__ __launch_bounds__(256) void attn_kernel(
    const u16* __restrict__ qkv, const u16* __restrict__ vt,
    u16* __restrict__ y) {
  __shared__ alignas(16) u16 Ks[2][64 * 64];
  __shared__ alignas(16) u16 VTs[2][64 * 64];
  __shared__ alignas(16) u16 Ps[4][16 * 64];
  const int tid = threadIdx.x;
  const int lane = tid & 63;
  const int w = tid >> 6;
  const int fr = lane & 15;
  const int fg = lane >> 4;
  const int hh = blockIdx.y;
  const int bb = blockIdx.z;
  const size_t tb = (size_t)bb * 2048 * 2304;
  const size_t vtb = (size_t)((bb * 12 + hh) * 64) * 2048;
  const int q0 = blockIdx.x * 64 + w * 16;

  const bf16x8 qf0 =
      *(const bf16x8*)&qkv[tb + (size_t)(q0 + fr) * 2304 + hh * 64 + fg * 8];
  const bf16x8 qf1 =
      *(const bf16x8*)&qkv[tb + (size_t)(q0 + fr) * 2304 + hh * 64 + 32 + fg * 8];

  f32x4 oacc[4] = {};
  float m = -INFINITY, l = 0.f;

  const int chunkrow = lane >> 3;
  const int chunkslot = lane & 7;

  auto stage = [&](int bufq, int kt) {
#pragma unroll
    for (int i = 0; i < 2; ++i) {
      const int row = (i * 4 + w) * 8 + chunkrow;
      const int slot = chunkslot ^ (row & 7);
      lds16(&Ks[bufq][(i * 4 + w) * 512],
            &qkv[tb + (size_t)(kt + row) * 2304 + 768 + hh * 64 + slot * 8]);
      lds16(&VTs[bufq][(i * 4 + w) * 512],
            &vt[vtb + (size_t)row * 2048 + kt + slot * 8]);
    }
  };

  stage(0, 0);
  int cur = 0;
  for (int kt = 0; kt < 2048; kt += 64) {
    __syncthreads();
    if (kt + 64 < 2048) stage(cur ^ 1, kt + 64);

    f32x4 s[4] = {};
#pragma unroll
    for (int kb = 0; kb < 4; ++kb) {
      const int row = kb * 16 + fr;
      const int sl0 = (fg) ^ (row & 7);
      const int sl1 = (4 + fg) ^ (row & 7);
      const bf16x8 k0 = *(const bf16x8*)&Ks[cur][row * 64 + sl0 * 8];
      const bf16x8 k1 = *(const bf16x8*)&Ks[cur][row * 64 + sl1 * 8];
      s[kb] = MFMA16(k0, qf0, s[kb]);
      s[kb] = MFMA16(k1, qf1, s[kb]);
    }

    float v[4][4];
    float mx = -INFINITY;
#pragma unroll
    for (int kb = 0; kb < 4; ++kb)
#pragma unroll
      for (int r = 0; r < 4; ++r) {
        v[kb][r] = s[kb][r] * 0.125f;
        mx = fmaxf(mx, v[kb][r]);
      }
    mx = fmaxf(mx, __shfl_xor(mx, 16));
    mx = fmaxf(mx, __shfl_xor(mx, 32));

    float alpha = 1.f;
    const bool resc = !__all(mx <= m);
    if (resc) {
      const float mn = fmaxf(m, mx);
      alpha = __expf(m - mn);
      m = mn;
    }

    float ps = 0.f;
    unsigned int pk[4][2];
#pragma unroll
    for (int kb = 0; kb < 4; ++kb) {
      const float p0 = __expf(v[kb][0] - m);
      const float p1 = __expf(v[kb][1] - m);
      const float p2 = __expf(v[kb][2] - m);
      const float p3 = __expf(v[kb][3] - m);
      ps += (p0 + p1) + (p2 + p3);
      pk[kb][0] = cvtpk(p0, p1);
      pk[kb][1] = cvtpk(p2, p3);
    }
    ps += __shfl_xor(ps, 16);
    ps += __shfl_xor(ps, 32);
    l = l * alpha + ps;

#pragma unroll
    for (int kb = 0; kb < 4; ++kb)
#pragma unroll
      for (int h = 0; h < 2; ++h) {
        const int off = fr * 64 + (((2 * kb + (fg >> 1)) ^ (fr & 7)) << 3) +
                        (2 * (fg & 1) + h) * 2;
        *(unsigned int*)&Ps[w][off] = pk[kb][h];
      }

    if (resc) {
      float alq[4];
#pragma unroll
      for (int r = 0; r < 4; ++r) alq[r] = __shfl(alpha, fg * 4 + r);
#pragma unroll
      for (int db = 0; db < 4; ++db)
#pragma unroll
        for (int r = 0; r < 4; ++r) oacc[db][r] *= alq[r];
    }

#pragma unroll
    for (int kh = 0; kh < 2; ++kh) {
      const bf16x8 pa =
          *(const bf16x8*)&Ps[w][fr * 64 + (((kh * 4 + fg) ^ (fr & 7)) << 3)];
#pragma unroll
      for (int db = 0; db < 4; ++db) {
        const int row = db * 16 + fr;
        const int slot = (kh * 4 + fg) ^ (row & 7);
        const bf16x8 vb = *(const bf16x8*)&VTs[cur][row * 64 + slot * 8];
        oacc[db] = MFMA16(pa, vb, oacc[db]);
      }
    }
    cur ^= 1;
  }

  float rq[4];
#pragma unroll
  for (int r = 0; r < 4; ++r) rq[r] = 1.0f / __shfl(l, fg * 4 + r);
#pragma unroll
  for (int db = 0; db < 4; ++db) {
#pragma unroll
    for (int r = 0; r < 4; ++r) {
      const int row = q0 + fg * 4 + r;
      y[(size_t)(bb * 2048 + row) * 768 + hh * 64 + db * 16 + fr] =
          f2b(oacc[db][r] * rq[r]);
    }
  }
}

// ---------------- launcher ---------------------------------------------------
extern "C" void kernel_launch(void* const* d_in, const int* in_sizes, int n_in,
                              void* d_out, int out_size, void* d_ws,
                              size_t ws_size, hipStream_t stream) {
  const int*   idx   = (const int*)d_in[0];
  const float* tok   = (const float*)d_in[1];
  const float* pos   = (const float*)d_in[2];
  const float* attnw = (const float*)d_in[3];
  const float* attnb = (const float*)d_in[4];
  const float* projw = (const float*)d_in[5];
  const float* projb = (const float*)d_in[6];
  const float* ln1g  = (const float*)d_in[7];
  const float* ln1b  = (const float*)d_in[8];
  const float* ln2g  = (const float*)d_in[9];
  const float* ln2b  = (const float*)d_in[10];
  const float* fc1w  = (const float*)d_in[11];
  const float* fc1b  = (const float*)d_in[12];
  const float* fc2w  = (const float*)d_in[13];
  const float* fc2b  = (const float*)d_in[14];
  const float* decw  = (const float*)d_in[15];

  char* ws = (char*)d_ws;
  float* x = (float*)(ws);                      // 4096*768 f32
  u16* h   = (u16*)(ws + 12582912);             // 4096*768 bf16
  u16* qkv = (u16*)(ws + 18874368);             // 4096*2304 bf16 (V part unused)
  u16* y   = (u16*)(ws + 37748736);             // 4096*768 bf16
  u16* h2  = (u16*)(ws + 18874368);             // alias qkv+y (MLP phase)

  const size_t WB0 = 44040192;
  u16* attnw_b = (u16*)(ws + WB0);
  u16* projw_b = (u16*)(ws + WB0 + 21233664);
  u16* fc1w_b  = (u16*)(ws + WB0 + 28311552);
  u16* fc2w_b  = (u16*)(ws + WB0 + 56623104);
  u16* decw_b  = (u16*)(ws + WB0 + 84934656);
  u16* vt      = (u16*)(ws + WB0 + 84934656 + 49152000);  // 4096*768 bf16
  const size_t NEED = WB0 + 84934656 + 49152000 + 12582912;  // 190,709,760 B

  embed_kernel<<<4096, 256, 0, stream>>>(idx, tok, pos, x);

  if (ws_size >= NEED) {
    conv5_kernel<<<dim3(1024, 5), 256, 0, stream>>>(
        attnw, attnw_b, 10616832 / 8, projw, projw_b, 3538944 / 8, fc1w,
        fc1w_b, 14155776 / 8, fc2w, fc2w_b, 14155776 / 8, decw, decw_b,
        24576000 / 8);

    for (int l = 0; l < 6; ++l) {
      ln_kernel<<<1024, 256, 0, stream>>>(x, ln1g + l * 768, ln1b + l * 768, h);
      gemmW<4><<<dim3(16, 18), 512, 147456, stream>>>(
          h, attnw_b + (size_t)l * 2304 * 768, attnb + l * 2304, qkv, nullptr,
          vt, 2304, 768);
      attn_kernel<<<dim3(32, 12, 2), 256, 0, stream>>>(qkv, vt, y);
      gemm_bb<5, 0, 2><<<dim3(6, 32, 2), 256, 0, stream>>>(
          y, projw_b + (size_t)l * 768 * 768, projb + l * 768, nullptr, nullptr,
          x, nullptr, 768, 768);
      ln_kernel<<<1024, 256, 0, stream>>>(x, ln2g + l * 768, ln2b + l * 768, h);
      gemmW<1><<<dim3(16, 24), 512, 147456, stream>>>(
          h, fc1w_b + (size_t)l * 3072 * 768, fc1b + l * 3072, h2, nullptr,
          nullptr, 3072, 768);
      gemm_bb<5, 0, 4><<<dim3(6, 32, 4), 256, 0, stream>>>(
          h2, fc2w_b + (size_t)l * 768 * 3072, fc2b + l * 768, nullptr, nullptr,
          x, nullptr, 768, 3072);
    }
    convh_kernel<<<1536, 256, 0, stream>>>(x, h);
    gemmW<3><<<dim3(16, 250), 512, 147456, stream>>>(
        h, decw_b, nullptr, nullptr, (float*)d_out, nullptr, 32000, 768);
  } else {
    for (int l = 0; l < 6; ++l) {
      ln_kernel<<<1024, 256, 0, stream>>>(x, ln1g + l * 768, ln1b + l * 768, h);
      gemm_bt<0><<<dim3(18, 32), 256, 0, stream>>>(
          h, attnw + (size_t)l * 2304 * 768, attnb + l * 2304, qkv, nullptr,
          nullptr, nullptr, 2304, 768);
      vtrans_kernel<<<dim3(32, 12, 2), 256, 0, stream>>>(
          qkv, (u16*)(ws + 12582912));
      attn_kernel<<<dim3(32, 12, 2), 256, 0, stream>>>(
          qkv, (u16*)(ws + 12582912), y);
      gemm_bt<2><<<dim3(6, 32), 256, 0, stream>>>(
          y, projw + (size_t)l * 768 * 768, projb + l * 768, nullptr, nullptr,
          x, nullptr, 768, 768);
      ln_kernel<<<1024, 256, 0, stream>>>(x, ln2g + l * 768, ln2b + l * 768, h);
      gemm_bt<1><<<dim3(24, 32), 256, 0, stream>>>(
          h, fc1w + (size_t)l * 3072 * 768, fc1b + l * 3072, h2, nullptr,
          nullptr, nullptr, 3072, 768);
      gemm_bt<2><<<dim3(6, 32), 256, 0, stream>>>(
          h2, fc2w + (size_t)l * 768 * 3072, fc2b + l * 768, nullptr, nullptr,
          x, (l == 5) ? h : nullptr, 768, 3072);
    }
    gemm_bt<3><<<dim3(250, 32), 256, 0, stream>>>(
        h, decw, nullptr, nullptr, (float*)d_out, nullptr, nullptr, 32000, 768);
  }
}

// Round 14
// 1736.391 us; speedup vs baseline: 1.0187x; 1.0187x over previous
//
#include <hip/hip_runtime.h>
#include <hip/hip_bf16.h>
#include <stdint.h>

// VanillaTransformer: V=32000 S=2048 D=768 H=12 HD=64 L=6, batch=2 -> 4096 tokens
// r14: r13 + gemmW MODE-3 epilogue rewritten as LDS-staged coalesced f32x4
// nontemporal writes (decoder was write-allocate-bound: 64B segment stores
// caused FETCH 206MB / WRITE 615MB vs 55/524 ideal). Values bitwise identical.

typedef unsigned short u16;
typedef __attribute__((ext_vector_type(8))) __bf16 bf16x8;
typedef __attribute__((ext_vector_type(4))) float f32x4;
typedef __attribute__((ext_vector_type(4))) unsigned int u32x4;
typedef __attribute__((ext_vector_type(4))) unsigned short u16x4;
typedef __attribute__((ext_vector_type(8))) unsigned short u16x8;

#define MFMA16(a, b, c) __builtin_amdgcn_mfma_f32_16x16x32_bf16((a), (b), (c), 0, 0, 0)

__device__ __forceinline__ float b2f(u16 u) {
  union { unsigned int i; float f; } x; x.i = ((unsigned int)u) << 16; return x.f;
}
__device__ __forceinline__ u16 f2b(float f) {  // round-to-nearest-even
  union { float f; unsigned int i; } x; x.f = f;
  unsigned int r = x.i + 0x7fffu + ((x.i >> 16) & 1u);
  return (u16)(r >> 16);
}
__device__ __forceinline__ unsigned int cvtpk(float lo, float hi) {
  unsigned int r;
  asm("v_cvt_pk_bf16_f32 %0, %1, %2" : "=v"(r) : "v"(lo), "v"(hi));
  return r;
}
__device__ __forceinline__ float gelu_f(float v) {  // tanh-approx (jax default)
  const float t = 0.7978845608028654f * (v + 0.044715f * v * v * v);
  const float e = __expf(-2.f * fabsf(t));
  float th = (1.f - e) / (1.f + e);
  th = (t < 0.f) ? -th : th;
  return 0.5f * v * (1.f + th);
}
__device__ __forceinline__ void lds16(u16* l, const u16* g) {
  __builtin_amdgcn_global_load_lds(
      (const __attribute__((address_space(1))) unsigned int*)g,
      (__attribute__((address_space(3))) unsigned int*)l, 16, 0, 0);
}

// ---------------- f32 -> bf16 conversion (all 5 weights, one launch) ---------
__global__ __launch_bounds__(256) void conv5_kernel(
    const float* __restrict__ s0, u16* __restrict__ d0, int n0,
    const float* __restrict__ s1, u16* __restrict__ d1, int n1,
    const float* __restrict__ s2, u16* __restrict__ d2, int n2,
    const float* __restrict__ s3, u16* __restrict__ d3, int n3,
    const float* __restrict__ s4, u16* __restrict__ d4, int n4) {
  const float* src; u16* dst; int n8;
  switch (blockIdx.y) {
    case 0: src = s0; dst = d0; n8 = n0; break;
    case 1: src = s1; dst = d1; n8 = n1; break;
    case 2: src = s2; dst = d2; n8 = n2; break;
    case 3: src = s3; dst = d3; n8 = n3; break;
    default: src = s4; dst = d4; n8 = n4; break;
  }
  int i = blockIdx.x * 256 + threadIdx.x;
  const int stride = gridDim.x * 256;
  for (; i < n8; i += stride) {
    const f32x4 a = *(const f32x4*)&src[(size_t)i * 8];
    const f32x4 b = *(const f32x4*)&src[(size_t)i * 8 + 4];
    u16x8 p;
#pragma unroll
    for (int j = 0; j < 4; ++j) { p[j] = f2b(a[j]); p[4 + j] = f2b(b[j]); }
    *(u16x8*)&dst[(size_t)i * 8] = p;
  }
}

// ---------------- f32 -> bf16 (x -> h before decoder) ------------------------
__global__ __launch_bounds__(256) void convh_kernel(
    const float* __restrict__ src, u16* __restrict__ dst) {
  const int i = blockIdx.x * 256 + threadIdx.x;  // n8 = 393216
  const f32x4 a = *(const f32x4*)&src[(size_t)i * 8];
  const f32x4 b = *(const f32x4*)&src[(size_t)i * 8 + 4];
  u16x8 p;
#pragma unroll
  for (int j = 0; j < 4; ++j) { p[j] = f2b(a[j]); p[4 + j] = f2b(b[j]); }
  *(u16x8*)&dst[(size_t)i * 8] = p;
}

// ---------------- embedding --------------------------------------------------
__global__ __launch_bounds__(256) void embed_kernel(
    const int* __restrict__ idx, const float* __restrict__ tok,
    const float* __restrict__ pos, float* __restrict__ x) {
  const int t = blockIdx.x;
  const int s = t & 2047;
  const int tid = threadIdx.x;
  const size_t to = (size_t)idx[t] * 768;
  const size_t po = (size_t)s * 768;
  float* xr = x + (size_t)t * 768;
#pragma unroll
  for (int i = 0; i < 3; ++i) {
    const int d = tid + i * 256;
    xr[d] = tok[to + d] + pos[po + d];
  }
}

// ---------------- LayerNorm: wave-per-row ------------------------------------
__global__ __launch_bounds__(256) void ln_kernel(
    const float* __restrict__ x, const float* __restrict__ g,
    const float* __restrict__ b, u16* __restrict__ out) {
  const int w = threadIdx.x >> 6, lane = threadIdx.x & 63;
  const int row = blockIdx.x * 4 + w;
  const float* xr = x + (size_t)row * 768;
  f32x4 v[3];
#pragma unroll
  for (int i = 0; i < 3; ++i) v[i] = *(const f32x4*)&xr[i * 256 + lane * 4];
  float s = 0.f;
#pragma unroll
  for (int i = 0; i < 3; ++i)
#pragma unroll
    for (int j = 0; j < 4; ++j) s += v[i][j];
#pragma unroll
  for (int m = 1; m < 64; m <<= 1) s += __shfl_xor(s, m);
  const float mu = s * (1.f / 768.f);
  float q = 0.f;
#pragma unroll
  for (int i = 0; i < 3; ++i)
#pragma unroll
    for (int j = 0; j < 4; ++j) {
      const float d = v[i][j] - mu;
      q += d * d;
    }
#pragma unroll
  for (int m = 1; m < 64; m <<= 1) q += __shfl_xor(q, m);
  const float rs = rsqrtf(q * (1.f / 768.f) + 1e-5f);
  u16* orow = out + (size_t)row * 768;
#pragma unroll
  for (int i = 0; i < 3; ++i) {
    const f32x4 gg = *(const f32x4*)&g[i * 256 + lane * 4];
    const f32x4 bb = *(const f32x4*)&b[i * 256 + lane * 4];
    u16x4 o;
#pragma unroll
    for (int j = 0; j < 4; ++j) o[j] = f2b((v[i][j] - mu) * rs * gg[j] + bb[j]);
    *(u16x4*)&orow[i * 256 + lane * 4] = o;
  }
}

// ===== gemmW: 256x128 tile, 8 waves (4M x 2N), BK=64, 3-buf counted-vmcnt ====
// LDS 147456 B = 3 bufs x 24576 u16; MODE-3 epilogue reuses it as f32[256][132].
// MODE 0: outb=bf16(acc+bias)  1: +gelu  3: outf f32 (LDS-staged coalesced nt)
// MODE 4: qkv epilogue (cols>=1536 -> V^T into mirror)
template <int MODE>
__global__ __launch_bounds__(512, 1) void gemmW(
    const u16* __restrict__ A, const u16* __restrict__ B,
    const float* __restrict__ bias, u16* __restrict__ outb,
    float* __restrict__ outf, u16* __restrict__ mirror, int N, int K) {
  extern __shared__ u16 smw[];  // 3 * 24576 u16 = 147456 B
  const int tid = threadIdx.x;
  const int lane = tid & 63;
  const int w = tid >> 6;
  const int wm = w >> 1;  // 0..3 (row 64-block)
  const int wn = w & 1;   // 0..1 (col 64-block)
  const int fr = lane & 15;
  const int fg = lane >> 4;
  const int bm0 = blockIdx.x * 256;
  const int bn0 = blockIdx.y * 128;
  const int nt = K >> 6;

  f32x4 acc[4][4] = {};

  auto stageT = [&](int buf, int t) {
    const int k0 = t << 6;
    u16* Ab = smw + buf * 24576;
    u16* Bb = smw + buf * 24576 + 16384;
#pragma unroll
    for (int i = 0; i < 4; ++i) {  // A: 2048 chunks of 16B
      const int c = i * 512 + tid;
      const int row = c >> 3;
      const int slot = (c & 7) ^ (row & 7);
      lds16(Ab + (i * 512 + w * 64) * 8,
            A + (size_t)(bm0 + row) * K + k0 + slot * 8);
    }
#pragma unroll
    for (int i = 0; i < 2; ++i) {  // B: 1024 chunks of 16B
      const int c = i * 512 + tid;
      const int row = c >> 3;
      const int slot = (c & 7) ^ (row & 7);
      lds16(Bb + (i * 512 + w * 64) * 8,
            B + (size_t)(bn0 + row) * K + k0 + slot * 8);
    }
  };

  stageT(0, 0);
  stageT(1, 1);
  int buf = 0;
  for (int t = 0; t < nt; ++t) {
    if (t + 1 < nt)
      asm volatile("s_waitcnt vmcnt(6)" ::: "memory");
    else
      asm volatile("s_waitcnt vmcnt(0)" ::: "memory");
    __builtin_amdgcn_sched_barrier(0);
    __builtin_amdgcn_s_barrier();
    __builtin_amdgcn_sched_barrier(0);
    if (t + 2 < nt) stageT((buf + 2) % 3, t + 2);
    const u16* Ab = smw + buf * 24576;
    const u16* Bb = smw + buf * 24576 + 16384;

    bf16x8 af[2][4], bfv[2][2];
#pragma unroll
    for (int kx = 0; kx < 2; ++kx)
#pragma unroll
      for (int m = 0; m < 4; ++m) {
        const int row = wm * 64 + m * 16 + fr;
        const int slot = (kx * 4 + fg) ^ (row & 7);
        af[kx][m] = *(const bf16x8*)&Ab[row * 64 + slot * 8];
      }
#pragma unroll
    for (int kx = 0; kx < 2; ++kx)
#pragma unroll
      for (int n = 0; n < 2; ++n) {
        const int row = wn * 64 + n * 16 + fr;
        const int slot = (kx * 4 + fg) ^ (row & 7);
        bfv[kx][n] = *(const bf16x8*)&Bb[row * 64 + slot * 8];
      }
    __builtin_amdgcn_s_setprio(1);
#pragma unroll
    for (int kx = 0; kx < 2; ++kx)
#pragma unroll
      for (int m = 0; m < 4; ++m)
#pragma unroll
        for (int n = 0; n < 2; ++n)
          acc[m][n] = MFMA16(af[kx][m], bfv[kx][n], acc[m][n]);
    __builtin_amdgcn_s_setprio(0);
#pragma unroll
    for (int kx = 0; kx < 2; ++kx)
#pragma unroll
      for (int n = 0; n < 2; ++n) {
        const int row = wn * 64 + (2 + n) * 16 + fr;
        const int slot = (kx * 4 + fg) ^ (row & 7);
        bfv[kx][n] = *(const bf16x8*)&Bb[row * 64 + slot * 8];
      }
    __builtin_amdgcn_s_setprio(1);
#pragma unroll
    for (int kx = 0; kx < 2; ++kx)
#pragma unroll
      for (int m = 0; m < 4; ++m)
#pragma unroll
        for (int n = 0; n < 2; ++n)
          acc[m][2 + n] = MFMA16(af[kx][m], bfv[kx][n], acc[m][2 + n]);
    __builtin_amdgcn_s_setprio(0);
    buf = (buf + 1) % 3;
  }

  if (MODE == 3) {
    // LDS-staged coalesced epilogue: acc -> LDS f32[256][132] -> f32x4 nt
    __syncthreads();  // all waves done reading staging buffers
    float* of = (float*)smw;
#pragma unroll
    for (int n = 0; n < 4; ++n) {
      const int col = wn * 64 + n * 16 + fr;
#pragma unroll
      for (int m = 0; m < 4; ++m) {
#pragma unroll
        for (int r = 0; r < 4; ++r) {
          const int row = wm * 64 + m * 16 + fg * 4 + r;
          of[row * 132 + col] = acc[m][n][r];
        }
      }
    }
    __syncthreads();
#pragma unroll
    for (int i = 0; i < 16; ++i) {
      const int c2 = i * 512 + tid;   // 8192 chunks of 16B
      const int row = c2 >> 5;        // 0..255
      const int cp = (c2 & 31) * 4;   // 0..124
      const f32x4 v = *(const f32x4*)&of[row * 132 + cp];
      __builtin_nontemporal_store(
          v, (f32x4*)&outf[(size_t)(bm0 + row) * N + bn0 + cp]);
    }
    return;
  }

  if (MODE == 4 && bn0 >= 1536) {
#pragma unroll
    for (int n = 0; n < 4; ++n) {
      const int col = bn0 + wn * 64 + n * 16 + fr;
      const float bv = bias[col];
      const int hcol = col - 1536;
      const size_t vbase =
          (size_t)(hcol >> 6) * 64 * 2048 + (size_t)(hcol & 63) * 2048;
#pragma unroll
      for (int m = 0; m < 4; ++m) {
        const int row0 = bm0 + wm * 64 + m * 16 + fg * 4;
        const size_t bboff = (size_t)(row0 >> 11) * 12 * 64 * 2048;
        const int s = row0 & 2047;
        u16x4 o;
#pragma unroll
        for (int r = 0; r < 4; ++r) o[r] = f2b(acc[m][n][r] + bv);
        *(u16x4*)&mirror[bboff + vbase + s] = o;
      }
    }
    return;
  }

#pragma unroll
  for (int n = 0; n < 4; ++n) {
    const int col = bn0 + wn * 64 + n * 16 + fr;
    const float bv = bias ? bias[col] : 0.0f;
#pragma unroll
    for (int m = 0; m < 4; ++m) {
#pragma unroll
      for (int r = 0; r < 4; ++r) {
        const int row = bm0 + wm * 64 + m * 16 + fg * 4 + r;
        float v = acc[m][n][r] + bv;
        if (MODE == 1) v = gelu_f(v);
        outb[(size_t)row * N + col] = f2b(v);
      }
    }
  }
}

// ===== gemm_bb 128^2, double-buffered, lds16+XOR swizzle =====================
// MODE 2: resid+= (RMW single owner)  5: atomicAdd (split-K; bias on z==0)
template <int MODE, int MFAST, int SPLITK>
__global__ __launch_bounds__(256) void gemm_bb(
    const u16* __restrict__ A, const u16* __restrict__ B,
    const float* __restrict__ bias, u16* __restrict__ outb,
    float* __restrict__ outf, float* __restrict__ resid,
    u16* __restrict__ mirror, int N, int K) {
  __shared__ alignas(16) u16 As[2][128 * 64];
  __shared__ alignas(16) u16 Bs[2][128 * 64];
  const int tid = threadIdx.x;
  const int lane = tid & 63;
  const int w = tid >> 6;
  const int wr = (w >> 1) * 64;
  const int wc = (w & 1) * 64;
  const int fr = lane & 15;
  const int fg = lane >> 4;
  const int bn0 = (MFAST ? blockIdx.y : blockIdx.x) * 128;
  const int bm0 = (MFAST ? blockIdx.x : blockIdx.y) * 128;
  const int srow = tid >> 3;
  const int kseg = K / SPLITK;
  const int kbeg = (SPLITK > 1) ? blockIdx.z * kseg : 0;
  const int kend = kbeg + kseg;

  f32x4 acc[4][4] = {};

  auto stage = [&](int bufq, int bk0) {
#pragma unroll
    for (int i = 0; i < 4; ++i) {
      const int row = i * 32 + srow;
      const int slot = (tid & 7) ^ (row & 7);
      lds16(&As[bufq][(i * 256 + w * 64) * 8],
            &A[(size_t)(bm0 + row) * K + bk0 + slot * 8]);
      lds16(&Bs[bufq][(i * 256 + w * 64) * 8],
            &B[(size_t)(bn0 + row) * K + bk0 + slot * 8]);
    }
  };

  stage(0, kbeg);
  int cur = 0;
  for (int bk0 = kbeg; bk0 < kend; bk0 += 64) {
    __syncthreads();
    if (bk0 + 64 < kend) stage(cur ^ 1, bk0 + 64);
#pragma unroll
    for (int kk = 0; kk < 64; kk += 32) {
      bf16x8 af[4], bfv[4];
#pragma unroll
      for (int m = 0; m < 4; ++m) {
        const int row = wr + m * 16 + fr;
        const int slot = ((kk >> 3) + fg) ^ (row & 7);
        af[m] = *(const bf16x8*)&As[cur][row * 64 + slot * 8];
      }
#pragma unroll
      for (int n = 0; n < 4; ++n) {
        const int row = wc + n * 16 + fr;
        const int slot = ((kk >> 3) + fg) ^ (row & 7);
        bfv[n] = *(const bf16x8*)&Bs[cur][row * 64 + slot * 8];
      }
#pragma unroll
      for (int m = 0; m < 4; ++m)
#pragma unroll
        for (int n = 0; n < 4; ++n)
          acc[m][n] = MFMA16(af[m], bfv[n], acc[m][n]);
    }
    cur ^= 1;
  }

#pragma unroll
  for (int n = 0; n < 4; ++n) {
    const int col = bn0 + wc + n * 16 + fr;
    const float bv =
        (bias && (SPLITK == 1 || blockIdx.z == 0)) ? bias[col] : 0.0f;
#pragma unroll
    for (int m = 0; m < 4; ++m) {
#pragma unroll
      for (int r = 0; r < 4; ++r) {
        const int row = bm0 + wr + m * 16 + fg * 4 + r;
        float v = acc[m][n][r] + bv;
        if (MODE == 1) v = gelu_f(v);
        const size_t off = (size_t)row * N + col;
        if (MODE == 2) {
          const float nv = resid[off] + v;
          resid[off] = nv;
          if (mirror) mirror[off] = f2b(nv);
        } else if (MODE == 5) {
          atomicAdd(&resid[off], v);
        } else if (MODE == 3) {
          __builtin_nontemporal_store(v, &outf[off]);
        } else {
          outb[off] = f2b(v);
        }
      }
    }
  }
}

// ===== fallback GEMM (B is f32, converted during staging) ====================
template <int MODE>
__global__ __launch_bounds__(256) void gemm_bt(
    const u16* __restrict__ A, const float* __restrict__ B,
    const float* __restrict__ bias, u16* __restrict__ outb,
    float* __restrict__ outf, float* __restrict__ resid,
    u16* __restrict__ mirror, int N, int K) {
  __shared__ alignas(16) u16 As[128 * 64];
  __shared__ alignas(16) u16 Bs[128 * 64];
  const int tid = threadIdx.x;
  const int lane = tid & 63;
  const int w = tid >> 6;
  const int wr = (w >> 1) * 64;
  const int wc = (w & 1) * 64;
  const int fr = lane & 15;
  const int fg = lane >> 4;
  const int bn0 = blockIdx.x * 128;
  const int bm0 = blockIdx.y * 128;

  f32x4 acc[4][4] = {};

  for (int bk0 = 0; bk0 < K; bk0 += 64) {
    __syncthreads();
#pragma unroll
    for (int i = 0; i < 4; ++i) {
      const int c = i * 256 + tid;
      const int row = c >> 3;
      const int e0 = (c & 7) * 8;
      *(u32x4*)&As[row * 64 + e0] =
          *(const u32x4*)&A[(size_t)(bm0 + row) * K + bk0 + e0];
    }
#pragma unroll
    for (int i = 0; i < 8; ++i) {
      const int c = i * 256 + tid;
      const int row = c >> 4;
      const int e0 = (c & 15) * 4;
      const f32x4 fv = *(const f32x4*)&B[(size_t)(bn0 + row) * K + bk0 + e0];
      u16x4 pv;
#pragma unroll
      for (int j = 0; j < 4; ++j) pv[j] = f2b(fv[j]);
      *(u16x4*)&Bs[row * 64 + e0] = pv;
    }
    __syncthreads();
#pragma unroll
    for (int kk = 0; kk < 64; kk += 32) {
      bf16x8 af[4], bfv[4];
#pragma unroll
      for (int m = 0; m < 4; ++m)
        af[m] = *(const bf16x8*)&As[(wr + m * 16 + fr) * 64 + kk + fg * 8];
#pragma unroll
      for (int n = 0; n < 4; ++n)
        bfv[n] = *(const bf16x8*)&Bs[(wc + n * 16 + fr) * 64 + kk + fg * 8];
#pragma unroll
      for (int m = 0; m < 4; ++m)
#pragma unroll
        for (int n = 0; n < 4; ++n)
          acc[m][n] = MFMA16(af[m], bfv[n], acc[m][n]);
    }
  }

#pragma unroll
  for (int n = 0; n < 4; ++n) {
    const int col = bn0 + wc + n * 16 + fr;
    const float bv = bias ? bias[col] : 0.0f;
#pragma unroll
    for (int m = 0; m < 4; ++m) {
#pragma unroll
      for (int r = 0; r < 4; ++r) {
        const int row = bm0 + wr + m * 16 + fg * 4 + r;
        float v = acc[m][n][r] + bv;
        if (MODE == 1) v = gelu_f(v);
        const size_t off = (size_t)row * N + col;
        if (MODE == 2) {
          const float nv = resid[off] + v;
          resid[off] = nv;
          if (mirror) mirror[off] = f2b(nv);
        } else if (MODE == 3) {
          __builtin_nontemporal_store(v, &outf[off]);
        } else {
          outb[off] = f2b(v);
        }
      }
    }
  }
}

// ---------------- V transpose (fallback path only) ---------------------------
__global__ __launch_bounds__(256) void vtrans_kernel(
    const u16* __restrict__ qkv, u16* __restrict__ vt) {
  __shared__ u16 tile[64][72];
  const int tid = threadIdx.x;
  const int s0 = blockIdx.x * 64;
  const int hh = blockIdx.y;
  const int bb = blockIdx.z;
  const size_t tb = (size_t)bb * 2048 * 2304;
#pragma unroll
  for (int i = 0; i < 2; ++i) {
    const int c = i * 256 + tid;
    const int sl = c >> 3;
    const int d0 = (c & 7) * 8;
    *(u16x8*)&tile[sl][d0] =
        *(const u16x8*)&qkv[tb + (size_t)(s0 + sl) * 2304 + 1536 + hh * 64 + d0];
  }
  __syncthreads();
  const size_t vtb = (size_t)((bb * 12 + hh) * 64) * 2048;
#pragma unroll
  for (int i = 0; i < 2; ++i) {
    const int c = i * 256 + tid;
    const int d = c >> 3;
    const int so = (c & 7) * 8;
    u16x8 p;
#pragma unroll
    for (int j = 0; j < 8; ++j) p[j] = tile[so + j][d];
    *(u16x8*)&vt[vtb + (size_t)d * 2048 + s0 + so] = p;
  }
}

// ---------------- fused attention v3 (proven): swapped QK^T ------------------
__global__ __launch_bounds__(256) void attn_kernel(
    const u16* __restrict__ qkv, const u16* __restrict__ vt,
    u16* __restrict__ y) {
  __shared__ alignas(16) u16 Ks[2][64 * 64];
  __shared__ alignas(16) u16 VTs[2][64 * 64];
  __shared__ alignas(16) u16 Ps[4][16 * 64];
  const int tid = threadIdx.x;
  const int lane = tid & 63;
  const int w = tid >> 6;
  const int fr = lane & 15;
  const int fg = lane >> 4;
  const int hh = blockIdx.y;
  const int bb = blockIdx.z;
  const size_t tb = (size_t)bb * 2048 * 2304;
  const size_t vtb = (size_t)((bb * 12 + hh) * 64) * 2048;
  const int q0 = blockIdx.x * 64 + w * 16;

  const bf16x8 qf0 =
      *(const bf16x8*)&qkv[tb + (size_t)(q0 + fr) * 2304 + hh * 64 + fg * 8];
  const bf16x8 qf1 =
      *(const bf16x8*)&qkv[tb + (size_t)(q0 + fr) * 2304 + hh * 64 + 32 + fg * 8];

  f32x4 oacc[4] = {};
  float m = -INFINITY, l = 0.f;

  const int chunkrow = lane >> 3;
  const int chunkslot = lane & 7;

  auto stage = [&](int bufq, int kt) {
#pragma unroll
    for (int i = 0; i < 2; ++i) {
      const int row = (i * 4 + w) * 8 + chunkrow;
      const int slot = chunkslot ^ (row & 7);
      lds16(&Ks[bufq][(i * 4 + w) * 512],
            &qkv[tb + (size_t)(kt + row) * 2304 + 768 + hh * 64 + slot * 8]);
      lds16(&VTs[bufq][(i * 4 + w) * 512],
            &vt[vtb + (size_t)row * 2048 + kt + slot * 8]);
    }
  };

  stage(0, 0);
  int cur = 0;
  for (int kt = 0; kt < 2048; kt += 64) {
    __syncthreads();
    if (kt + 64 < 2048) stage(cur ^ 1, kt + 64);

    f32x4 s[4] = {};
#pragma unroll
    for (int kb = 0; kb < 4; ++kb) {
      const int row = kb * 16 + fr;
      const int sl0 = (fg) ^ (row & 7);
      const int sl1 = (4 + fg) ^ (row & 7);
      const bf16x8 k0 = *(const bf16x8*)&Ks[cur][row * 64 + sl0 * 8];
      const bf16x8 k1 = *(const bf16x8*)&Ks[cur][row * 64 + sl1 * 8];
      s[kb] = MFMA16(k0, qf0, s[kb]);
      s[kb] = MFMA16(k1, qf1, s[kb]);
    }

    float v[4][4];
    float mx = -INFINITY;
#pragma unroll
    for (int kb = 0; kb < 4; ++kb)
#pragma unroll
      for (int r = 0; r < 4; ++r) {
        v[kb][r] = s[kb][r] * 0.125f;
        mx = fmaxf(mx, v[kb][r]);
      }
    mx = fmaxf(mx, __shfl_xor(mx, 16));
    mx = fmaxf(mx, __shfl_xor(mx, 32));

    float alpha = 1.f;
    const bool resc = !__all(mx <= m);
    if (resc) {
      const float mn = fmaxf(m, mx);
      alpha = __expf(m - mn);
      m = mn;
    }

    float ps = 0.f;
    unsigned int pk[4][2];
#pragma unroll
    for (int kb = 0; kb < 4; ++kb) {
      const float p0 = __expf(v[kb][0] - m);
      const float p1 = __expf(v[kb][1] - m);
      const float p2 = __expf(v[kb][2] - m);
      const float p3 = __expf(v[kb][3] - m);
      ps += (p0 + p1) + (p2 + p3);
      pk[kb][0] = cvtpk(p0, p1);
      pk[kb][1] = cvtpk(p2, p3);
    }
    ps += __shfl_xor(ps, 16);
    ps += __shfl_xor(ps, 32);
    l = l * alpha + ps;

#pragma unroll
    for (int kb = 0; kb < 4; ++kb)
#pragma unroll
      for (int h = 0; h < 2; ++h) {
        const int off = fr * 64 + (((2 * kb + (fg >> 1)) ^ (fr & 7)) << 3) +
                        (2 * (fg & 1) + h) * 2;
        *(unsigned int*)&Ps[w][off] = pk[kb][h];
      }

    if (resc) {
      float alq[4];
#pragma unroll
      for (int r = 0; r < 4; ++r) alq[r] = __shfl(alpha, fg * 4 + r);
#pragma unroll
      for (int db = 0; db < 4; ++db)
#pragma unroll
        for (int r = 0; r < 4; ++r) oacc[db][r] *= alq[r];
    }

#pragma unroll
    for (int kh = 0; kh < 2; ++kh) {
      const bf16x8 pa =
          *(const bf16x8*)&Ps[w][fr * 64 + (((kh * 4 + fg) ^ (fr & 7)) << 3)];
#pragma unroll
      for (int db = 0; db < 4; ++db) {
        const int row = db * 16 + fr;
        const int slot = (kh * 4 + fg) ^ (row & 7);
        const bf16x8 vb = *(const bf16x8*)&VTs[cur][row * 64 + slot * 8];
        oacc[db] = MFMA16(pa, vb, oacc[db]);
      }
    }
    cur ^= 1;
  }

  float rq[4];
#pragma unroll
  for (int r = 0; r < 4; ++r) rq[r] = 1.0f / __shfl(l, fg * 4 + r);
#pragma unroll
  for (int db = 0; db < 4; ++db) {
#pragma unroll
    for (int r = 0; r < 4; ++r) {
      const int row = q0 + fg * 4 + r;
      y[(size_t)(bb * 2048 + row) * 768 + hh * 64 + db * 16 + fr] =
          f2b(oacc[db][r] * rq[r]);
    }
  }
}

// ---------------- launcher ---------------------------------------------------
extern "C" void kernel_launch(void* const* d_in, const int* in_sizes, int n_in,
                              void* d_out, int out_size, void* d_ws,
                              size_t ws_size, hipStream_t stream) {
  const int*   idx   = (const int*)d_in[0];
  const float* tok   = (const float*)d_in[1];
  const float* pos   = (const float*)d_in[2];
  const float* attnw = (const float*)d_in[3];
  const float* attnb = (const float*)d_in[4];
  const float* projw = (const float*)d_in[5];
  const float* projb = (const float*)d_in[6];
  const float* ln1g  = (const float*)d_in[7];
  const float* ln1b  = (const float*)d_in[8];
  const float* ln2g  = (const float*)d_in[9];
  const float* ln2b  = (const float*)d_in[10];
  const float* fc1w  = (const float*)d_in[11];
  const float* fc1b  = (const float*)d_in[12];
  const float* fc2w  = (const float*)d_in[13];
  const float* fc2b  = (const float*)d_in[14];
  const float* decw  = (const float*)d_in[15];

  char* ws = (char*)d_ws;
  float* x = (float*)(ws);                      // 4096*768 f32
  u16* h   = (u16*)(ws + 12582912);             // 4096*768 bf16
  u16* qkv = (u16*)(ws + 18874368);             // 4096*2304 bf16 (V part unused)
  u16* y   = (u16*)(ws + 37748736);             // 4096*768 bf16
  u16* h2  = (u16*)(ws + 18874368);             // alias qkv+y (MLP phase)

  const size_t WB0 = 44040192;
  u16* attnw_b = (u16*)(ws + WB0);
  u16* projw_b = (u16*)(ws + WB0 + 21233664);
  u16* fc1w_b  = (u16*)(ws + WB0 + 28311552);
  u16* fc2w_b  = (u16*)(ws + WB0 + 56623104);
  u16* decw_b  = (u16*)(ws + WB0 + 84934656);
  u16* vt      = (u16*)(ws + WB0 + 84934656 + 49152000);  // 4096*768 bf16
  const size_t NEED = WB0 + 84934656 + 49152000 + 12582912;  // 190,709,760 B

  embed_kernel<<<4096, 256, 0, stream>>>(idx, tok, pos, x);

  if (ws_size >= NEED) {
    conv5_kernel<<<dim3(1024, 5), 256, 0, stream>>>(
        attnw, attnw_b, 10616832 / 8, projw, projw_b, 3538944 / 8, fc1w,
        fc1w_b, 14155776 / 8, fc2w, fc2w_b, 14155776 / 8, decw, decw_b,
        24576000 / 8);

    for (int l = 0; l < 6; ++l) {
      ln_kernel<<<1024, 256, 0, stream>>>(x, ln1g + l * 768, ln1b + l * 768, h);
      gemmW<4><<<dim3(16, 18), 512, 147456, stream>>>(
          h, attnw_b + (size_t)l * 2304 * 768, attnb + l * 2304, qkv, nullptr,
          vt, 2304, 768);
      attn_kernel<<<dim3(32, 12, 2), 256, 0, stream>>>(qkv, vt, y);
      gemm_bb<5, 0, 2><<<dim3(6, 32, 2), 256, 0, stream>>>(
          y, projw_b + (size_t)l * 768 * 768, projb + l * 768, nullptr, nullptr,
          x, nullptr, 768, 768);
      ln_kernel<<<1024, 256, 0, stream>>>(x, ln2g + l * 768, ln2b + l * 768, h);
      gemmW<1><<<dim3(16, 24), 512, 147456, stream>>>(
          h, fc1w_b + (size_t)l * 3072 * 768, fc1b + l * 3072, h2, nullptr,
          nullptr, 3072, 768);
      gemm_bb<5, 0, 4><<<dim3(6, 32, 4), 256, 0, stream>>>(
          h2, fc2w_b + (size_t)l * 768 * 3072, fc2b + l * 768, nullptr, nullptr,
          x, nullptr, 768, 3072);
    }
    convh_kernel<<<1536, 256, 0, stream>>>(x, h);
    gemmW<3><<<dim3(16, 250), 512, 147456, stream>>>(
        h, decw_b, nullptr, nullptr, (float*)d_out, nullptr, 32000, 768);
  } else {
    for (int l = 0; l < 6; ++l) {
      ln_kernel<<<1024, 256, 0, stream>>>(x, ln1g + l * 768, ln1b + l * 768, h);
      gemm_bt<0><<<dim3(18, 32), 256, 0, stream>>>(
          h, attnw + (size_t)l * 2304 * 768, attnb + l * 2304, qkv, nullptr,
          nullptr, nullptr, 2304, 768);
      vtrans_kernel<<<dim3(32, 12, 2), 256, 0, stream>>>(
          qkv, (u16*)(ws + 12582912));
      attn_kernel<<<dim3(32, 12, 2), 256, 0, stream>>>(
          qkv, (u16*)(ws + 12582912), y);
      gemm_bt<2><<<dim3(6, 32), 256, 0, stream>>>(
          y, projw + (size_t)l * 768 * 768, projb + l * 768, nullptr, nullptr,
          x, nullptr, 768, 768);
      ln_kernel<<<1024, 256, 0, stream>>>(x, ln2g + l * 768, ln2b + l * 768, h);
      gemm_bt<1><<<dim3(24, 32), 256, 0, stream>>>(
          h, fc1w + (size_t)l * 3072 * 768, fc1b + l * 3072, h2, nullptr,
          nullptr, nullptr, 3072, 768);
      gemm_bt<2><<<dim3(6, 32), 256, 0, stream>>>(
          h2, fc2w + (size_t)l * 768 * 3072, fc2b + l * 768, nullptr, nullptr,
          x, (l == 5) ? h : nullptr, 768, 3072);
    }
    gemm_bt<3><<<dim3(250, 32), 256, 0, stream>>>(
        h, decw, nullptr, nullptr, (float*)d_out, nullptr, nullptr, 32000, 768);
  }
}